// Round 8
// baseline (174.018 us; speedup 1.0000x reference)
//
#include <hip/hip_runtime.h>
#include <hip/hip_fp16.h>

#define D 128
#define BSHIFT 6
#define BSIZE 64         // nodes per bucket
#define NBMAX 1024       // supports N <= 65536 (and N <= 2^26 for packing)
#define BCAP 3072        // slab capacity per bucket (E[cnt]=2046, >20 sigma safe)
#define CPAD 16          // bucket_cnt stride (ints): one counter per 64B line
#define PREP_BLOCKS 256  // 1 block/CU; 512 measured WORSE (phase-2 atomic tail, r3)
#define OVF_CAP 65536
#define GB_THREADS 1024  // gatherB block: 16 waves, one bucket per block

// r5 post-mortem: one-writer/global-broadcast W staging diverged on graph
// replay — W fragment staging stays per-block in LDS.
// r7 post-mortem: gatherB invariant at 42.4us under gather ILP restructure ->
// pattern-bandwidth-bound; this round overlaps prep||xw instead (fused kernel,
// un-normalized xw', dinv applied via fma in gatherB).

using half8 = __attribute__((ext_vector_type(8))) _Float16;
using float4v = __attribute__((ext_vector_type(4))) float;
using floatx2 = __attribute__((ext_vector_type(2))) float;

// ---- fused kernel: blocks [0,PREP_BLOCKS) = prep ; [PREP_BLOCKS, +NB) = xw --
// The two roles share NO data (xw' is un-normalized), so they overlap freely.
__global__ __launch_bounds__(256) void fused_kernel(const int* __restrict__ src,
                                                    const int* __restrict__ dst,
                                                    const float* __restrict__ x,
                                                    const float* __restrict__ W,
                                                    int* __restrict__ bucket_cnt,
                                                    int* __restrict__ pairs,
                                                    int* __restrict__ ovfA_cnt,
                                                    int2* __restrict__ ovfA,
                                                    unsigned char* __restrict__ xw,
                                                    int E, int NB, int N) {
    __shared__ __align__(16) char smem_raw[32768];  // prep: 8KB hist; xw: 32KB Bf
    const int t = threadIdx.x;

    if (blockIdx.x < PREP_BLOCKS) {
        // ================= prep role =================
        int* sbase = (int*)smem_raw;          // NBMAX ints
        int* cur = sbase + NBMAX;             // NBMAX ints
        for (int b = t; b < NB; b += 256) { sbase[b] = 0; cur[b] = 0; }
        __syncthreads();

        int chunk = (((E + PREP_BLOCKS - 1) / PREP_BLOCKS) + 3) & ~3;  // 4-aligned
        int start = blockIdx.x * chunk;
        int end = min(start + chunk, E);

        // phase 1: histogram dst>>6 for this chunk
        for (int i = start + 4 * t; i < end; i += 4 * 256) {
            if (i + 3 < end) {
                int4 v = *(const int4*)&dst[i];
                atomicAdd(&sbase[v.x >> BSHIFT], 1);
                atomicAdd(&sbase[v.y >> BSHIFT], 1);
                atomicAdd(&sbase[v.z >> BSHIFT], 1);
                atomicAdd(&sbase[v.w >> BSHIFT], 1);
            } else {
                for (int j = i; j < end; ++j) atomicAdd(&sbase[dst[j] >> BSHIFT], 1);
            }
        }
        __syncthreads();

        // phase 2: reserve contiguous ranges (padded counters, no line sharing)
        for (int b = t; b < NB; b += 256) {
            int h = sbase[b];
            sbase[b] = h ? atomicAdd(&bucket_cnt[b * CPAD], h) : 0;
        }
        __syncthreads();

        // phase 3: replay chunk (L2-hot) and place packed (src<<6)|dl
        auto place = [&](int dd, int ss) {
            int b = dd >> BSHIFT;
            int p = sbase[b] + atomicAdd(&cur[b], 1);
            if (p < BCAP) {
                pairs[(size_t)b * BCAP + p] = (ss << BSHIFT) | (dd & (BSIZE - 1));
            } else {  // slab overflow (statistically never)
                int q = atomicAdd(ovfA_cnt, 1);
                if (q < OVF_CAP) ovfA[q] = make_int2(dd, ss);
            }
        };
        for (int i = start + 4 * t; i < end; i += 4 * 256) {
            if (i + 3 < end) {
                int4 dv = *(const int4*)&dst[i];
                int4 sv = *(const int4*)&src[i];
                place(dv.x, sv.x);
                place(dv.y, sv.y);
                place(dv.z, sv.z);
                place(dv.w, sv.w);
            } else {
                for (int j = i; j < end; ++j) place(dst[j], src[j]);
            }
        }
    } else {
        // ================= xw role: xw' = fp8(x @ W^T), UN-normalized =========
        // MFMA 16x16x32_f16: A[m=lane&15][k=(lane>>4)*8+j]; B[k][n=lane&15];
        // D: col=lane&15, row=(lane>>4)*4+reg.
        // xw[row] = 128 fp8 bytes, byte sigma(col) = (col%16)*8 + col/16.
        const int b = blockIdx.x - PREP_BLOCKS;
        _Float16* Bf = (_Float16*)smem_raw;  // 128*128 f16, fragment-ordered

        {
            int n = t >> 1;
            int jt = n >> 4, nlo = n & 15;
            int kbase = (t & 1) * 64;
#pragma unroll
            for (int o = 0; o < 8; ++o) {
                int k0 = kbase + o * 8;
                float4 f0 = *(const float4*)&W[n * 128 + k0];
                float4 f1 = *(const float4*)&W[n * 128 + k0 + 4];
                int kt = k0 >> 5, quad = (k0 >> 3) & 3;
                half8 h;
                h[0] = (_Float16)f0.x; h[1] = (_Float16)f0.y;
                h[2] = (_Float16)f0.z; h[3] = (_Float16)f0.w;
                h[4] = (_Float16)f1.x; h[5] = (_Float16)f1.y;
                h[6] = (_Float16)f1.z; h[7] = (_Float16)f1.w;
                *(half8*)&Bf[(size_t)(((kt * 8 + jt) * 4 + quad) * 16 + nlo) * 8] = h;
            }
        }
        __syncthreads();

        const int lane = t & 63;
        const int quad = lane >> 4, nlo = lane & 15;
        const int r0 = b * 64 + (t >> 6) * 16;
        const int rA = r0 + nlo;
        const int rAc = (rA < N) ? rA : (N - 1);

        float4v acc[8];
#pragma unroll
        for (int j = 0; j < 8; ++j) acc[j] = (float4v){0.f, 0.f, 0.f, 0.f};

#pragma unroll
        for (int kt = 0; kt < 4; ++kt) {
            const float* xp = x + (size_t)rAc * D + kt * 32 + quad * 8;
            float4 a0 = *(const float4*)xp;
            float4 a1 = *(const float4*)(xp + 4);
            half8 va;
            va[0] = (_Float16)a0.x; va[1] = (_Float16)a0.y;
            va[2] = (_Float16)a0.z; va[3] = (_Float16)a0.w;
            va[4] = (_Float16)a1.x; va[5] = (_Float16)a1.y;
            va[6] = (_Float16)a1.z; va[7] = (_Float16)a1.w;
#pragma unroll
            for (int jt = 0; jt < 8; ++jt) {
                half8 vb = *(half8*)&Bf[(size_t)((kt * 8 + jt) * 64 + lane) * 8];
                acc[jt] = __builtin_amdgcn_mfma_f32_16x16x32_f16(va, vb, acc[jt], 0, 0, 0);
            }
        }

#pragma unroll
        for (int reg = 0; reg < 4; ++reg) {
            int row = r0 + quad * 4 + reg;
            if (row < N) {
                int u0 = __builtin_amdgcn_cvt_pk_fp8_f32(acc[0][reg], acc[1][reg], 0, false);
                u0 = __builtin_amdgcn_cvt_pk_fp8_f32(acc[2][reg], acc[3][reg], u0, true);
                int u1 = __builtin_amdgcn_cvt_pk_fp8_f32(acc[4][reg], acc[5][reg], 0, false);
                u1 = __builtin_amdgcn_cvt_pk_fp8_f32(acc[6][reg], acc[7][reg], u1, true);
                *(uint2*)(xw + (size_t)row * 128 + nlo * 8) = make_uint2((unsigned)u0, (unsigned)u1);
            }
        }
    }
}

// ---- dinv table: per-node rsqrt(deg+1), from slabs + spills (~4us) ----------
__global__ __launch_bounds__(256) void dinv_kernel(const int* __restrict__ pairs,
                                                   const int* __restrict__ bucket_cnt,
                                                   const int* __restrict__ ovfA_cnt,
                                                   const int2* __restrict__ ovfA,
                                                   float* __restrict__ dinvTab, int N) {
    __shared__ int degX[BSIZE];
    const int t = threadIdx.x;
    const int b = blockIdx.x;
    if (t < BSIZE) degX[t] = 0;
    __syncthreads();
    int cnt = min(bucket_cnt[b * CPAD], BCAP);
    const int* pp = pairs + (size_t)b * BCAP;
    for (int i = t; i < cnt; i += 256) atomicAdd(&degX[pp[i] & (BSIZE - 1)], 1);
    int na = *ovfA_cnt;
    if (na > 0) {
        if (na > OVF_CAP) na = OVF_CAP;
        for (int k = t; k < na; k += 256) {
            int dd = ovfA[k].x;
            if ((dd >> BSHIFT) == b) atomicAdd(&degX[dd & (BSIZE - 1)], 1);
        }
    }
    __syncthreads();
    if (t < BSIZE) {
        int node = b * BSIZE + t;
        if (node < N) dinvTab[node] = rsqrtf((float)degX[t] + 1.0f);
    }
}

// ---------------- gatherB: counting sort (src,dinv) + uint2 gather + fma -----
// Inner loop: ds_read_b64 of (src, dinv[src]) + same uint2 row gather; the
// dinv[src] scale rides the accumulate as fma (same VALU count as the add).
// dinvTab loads happen in stage 1a (off the critical loop). Self term scales
// by dvd, spills by dinvTab[src]; epilogue multiplies by dvd (= dinv[dst]).
// out[d][c] = x[d][c] + relu(dinv_d*(dinv_d*xw'[d] + sum_e dinv_s*xw'[s]) + b[c])
// byte s of a row = col ((s%8)*16 + s/8.
__global__ __launch_bounds__(GB_THREADS) void gatherB_kernel(
    const float* __restrict__ x, const unsigned char* __restrict__ xw,
    const int* __restrict__ pairs, const int* __restrict__ bucket_cnt,
    const float* __restrict__ bias, const int* __restrict__ ovfA_cnt,
    const int2* __restrict__ ovfA, const float* __restrict__ dinvTab,
    float* __restrict__ out, int N) {
    __shared__ int2 lds2[BCAP];            // 24 KB: (src, dinv bits)
    __shared__ int degL[BSIZE], offs[BSIZE], cur[BSIZE], spillc[BSIZE];
    const int b = blockIdx.x;
    const int t = threadIdx.x;
    if (t < BSIZE) { degL[t] = 0; cur[t] = 0; spillc[t] = 0; }
    __syncthreads();
    const int cnt = min(bucket_cnt[b * CPAD], BCAP);
    int na = *ovfA_cnt;
    if (na > OVF_CAP) na = OVF_CAP;

    // stage 1a: load pairs (3 static peels) + hist + fetch dinv[src] (L2-hot)
    const int* slab = pairs + (size_t)b * BCAP;
    int w0 = 0, w1 = 0, w2 = 0;
    float s0f = 0.f, s1f = 0.f, s2f = 0.f;
    const bool p0 = t < cnt, p1 = t + 1024 < cnt, p2 = t + 2048 < cnt;
    if (p0) { w0 = slab[t];        atomicAdd(&degL[w0 & (BSIZE - 1)], 1); s0f = dinvTab[w0 >> BSHIFT]; }
    if (p1) { w1 = slab[t + 1024]; atomicAdd(&degL[w1 & (BSIZE - 1)], 1); s1f = dinvTab[w1 >> BSHIFT]; }
    if (p2) { w2 = slab[t + 2048]; atomicAdd(&degL[w2 & (BSIZE - 1)], 1); s2f = dinvTab[w2 >> BSHIFT]; }
    if (na > 0) {
        for (int k = t; k < na; k += GB_THREADS) {
            int dd = ovfA[k].x;
            if ((dd >> BSHIFT) == b) atomicAdd(&spillc[dd & (BSIZE - 1)], 1);
        }
    }
    __syncthreads();

    // stage 1b: exclusive scan of degL (wave 0)
    if (t < BSIZE) {
        int v = degL[t];
        int s = v;
#pragma unroll
        for (int o = 1; o < 64; o <<= 1) {
            int u = __shfl_up(s, o, 64);
            if (t >= o) s += u;
        }
        offs[t] = s - v;
    }
    __syncthreads();

    // stage 1c: scatter (src, dinv) into node-sorted LDS list
    if (p0) { int dl = w0 & (BSIZE - 1); lds2[offs[dl] + atomicAdd(&cur[dl], 1)] = make_int2(w0 >> BSHIFT, __float_as_int(s0f)); }
    if (p1) { int dl = w1 & (BSIZE - 1); lds2[offs[dl] + atomicAdd(&cur[dl], 1)] = make_int2(w1 >> BSHIFT, __float_as_int(s1f)); }
    if (p2) { int dl = w2 & (BSIZE - 1); lds2[offs[dl] + atomicAdd(&cur[dl], 1)] = make_int2(w2 >> BSHIFT, __float_as_int(s2f)); }
    __syncthreads();

    // stage 2: wave w handles nodes dl = 4w..4w+3; 4 lane-groups of 16
    const int wave = t >> 6, lane = t & 63;
    const int g = lane >> 4, c15 = lane & 15;
    const uint2* xw64 = (const uint2*)xw;  // row r at r*16 + c15 (8B each)

    const int sb0 = c15 * 8 + 2 * g, sb1 = sb0 + 1;
    const int colA = ((sb0 & 7) << 4) + (sb0 >> 3);
    const int colB = ((sb1 & 7) << 4) + (sb1 >> 3);
    const float bA = bias[colA], bB = bias[colB];

    for (int q = 0; q < 4; ++q) {
        int dl = wave * 4 + q;
        int node = b * BSIZE + dl;
        if (node >= N) break;  // wave-uniform
        int start = offs[dl];
        int end = start + degL[dl];
        float dvd = rsqrtf((float)(degL[dl] + spillc[dl]) + 1.0f);
        size_t noff = (size_t)node * D;

        float a0 = 0.f, a1 = 0.f, a2 = 0.f, a3 = 0.f;
        float a4 = 0.f, a5 = 0.f, a6 = 0.f, a7 = 0.f;

#define ACC8(v, s)                                                           \
    {                                                                        \
        floatx2 q0 = __builtin_amdgcn_cvt_pk_f32_fp8((int)(v).x, false);     \
        floatx2 q1 = __builtin_amdgcn_cvt_pk_f32_fp8((int)(v).x, true);      \
        floatx2 q2 = __builtin_amdgcn_cvt_pk_f32_fp8((int)(v).y, false);     \
        floatx2 q3 = __builtin_amdgcn_cvt_pk_f32_fp8((int)(v).y, true);      \
        a0 += q0.x * (s); a1 += q0.y * (s); a2 += q1.x * (s); a3 += q1.y * (s); \
        a4 += q2.x * (s); a5 += q2.y * (s); a6 += q3.x * (s); a7 += q3.y * (s); \
    }

        int e = start;
        for (; e + 15 < end; e += 16) {  // 4 independent row loads in flight
            int2 e0 = lds2[e + 0 + g], e1 = lds2[e + 4 + g];
            int2 e2 = lds2[e + 8 + g], e3 = lds2[e + 12 + g];
            uint2 v0 = xw64[(size_t)e0.x * 16 + c15];
            uint2 v1 = xw64[(size_t)e1.x * 16 + c15];
            uint2 v2 = xw64[(size_t)e2.x * 16 + c15];
            uint2 v3 = xw64[(size_t)e3.x * 16 + c15];
            ACC8(v0, __int_as_float(e0.y))
            ACC8(v1, __int_as_float(e1.y))
            ACC8(v2, __int_as_float(e2.y))
            ACC8(v3, __int_as_float(e3.y))
        }
        for (; e < end; e += 4) {  // masked tail, zero-fill inactive groups
            int idx = e + g;
            uint2 v = make_uint2(0u, 0u);
            float s = 0.f;
            if (idx < end) {
                int2 pr = lds2[idx];
                v = xw64[(size_t)pr.x * 16 + c15];
                s = __int_as_float(pr.y);
            }
            ACC8(v, s)
        }

        // combine the 4 lane-groups
        a0 += __shfl_xor(a0, 16); a0 += __shfl_xor(a0, 32);
        a1 += __shfl_xor(a1, 16); a1 += __shfl_xor(a1, 32);
        a2 += __shfl_xor(a2, 16); a2 += __shfl_xor(a2, 32);
        a3 += __shfl_xor(a3, 16); a3 += __shfl_xor(a3, 32);
        a4 += __shfl_xor(a4, 16); a4 += __shfl_xor(a4, 32);
        a5 += __shfl_xor(a5, 16); a5 += __shfl_xor(a5, 32);
        a6 += __shfl_xor(a6, 16); a6 += __shfl_xor(a6, 32);
        a7 += __shfl_xor(a7, 16); a7 += __shfl_xor(a7, 32);

        // self term (scale dvd) + spills (scale dinvTab[src])
        {
            uint2 vs = xw64[(size_t)node * 16 + c15];
            ACC8(vs, dvd)
            if (na > 0) {
                for (int k = 0; k < na; ++k) {
                    int2 pr = ovfA[k];
                    if (pr.x == node) {
                        uint2 v = xw64[(size_t)pr.y * 16 + c15];
                        ACC8(v, dinvTab[pr.y])
                    }
                }
            }
        }
#undef ACC8

        // epilogue: group g writes cols k=2g, 2g+1
        float sA = (g == 0) ? a0 : (g == 1) ? a2 : (g == 2) ? a4 : a6;
        float sB = (g == 0) ? a1 : (g == 1) ? a3 : (g == 2) ? a5 : a7;
        float hA = sA * dvd + bA;
        float hB = sB * dvd + bB;
        out[noff + colA] = x[noff + colA] + (hA > 0.f ? hA : 0.f);
        out[noff + colB] = x[noff + colB] + (hB > 0.f ? hB : 0.f);
    }
}

extern "C" void kernel_launch(void* const* d_in, const int* in_sizes, int n_in,
                              void* d_out, int out_size, void* d_ws, size_t ws_size,
                              hipStream_t stream) {
    const float* x = (const float*)d_in[0];
    const int* ei = (const int*)d_in[1];
    const float* W = (const float*)d_in[2];
    const float* bias = (const float*)d_in[3];
    float* out = (float*)d_out;

    const int N = in_sizes[0] / D;   // 50000
    const int E = in_sizes[1] / 2;   // 1,600,000
    const int* src = ei;
    const int* dst = ei + E;
    const int NB = (N + BSIZE - 1) / BSIZE;  // 782 (<= NBMAX)

    // workspace (~17.3 MB); bucket_cnt (padded) + ovfA_cnt adjacent -> one memset
    char* p = (char*)d_ws;
    int* pairs = (int*)p;            p += (size_t)NB * BCAP * sizeof(int);      // 9.6 MB
    unsigned char* xw = (unsigned char*)p; p += (size_t)N * 128;                // 6.4 MB
    int* bucket_cnt = (int*)p;       p += (size_t)NBMAX * CPAD * sizeof(int);   // 64 KB
    int* ovfA_cnt = (int*)p;         p += 16;
    int2* ovfA = (int2*)p;           p += (size_t)OVF_CAP * sizeof(int2);       // 0.5 MB
    float* dinvTab = (float*)p;      p += (size_t)NBMAX * BSIZE * sizeof(float);// 256 KB

    hipMemsetAsync(bucket_cnt, 0, (size_t)NBMAX * CPAD * sizeof(int) + 16, stream);

    fused_kernel<<<PREP_BLOCKS + NB, 256, 0, stream>>>(src, dst, x, W, bucket_cnt,
                                                       pairs, ovfA_cnt, ovfA, xw,
                                                       E, NB, N);
    dinv_kernel<<<NB, 256, 0, stream>>>(pairs, bucket_cnt, ovfA_cnt, ovfA, dinvTab, N);
    gatherB_kernel<<<NB, GB_THREADS, 0, stream>>>(x, xw, pairs, bucket_cnt,
                                                  bias, ovfA_cnt, ovfA, dinvTab, out, N);
}

// Round 9
// 158.590 us; speedup vs baseline: 1.0973x; 1.0973x over previous
//
#include <hip/hip_runtime.h>
#include <hip/hip_fp16.h>

#define D 128
#define BSHIFT 6
#define BSIZE 64         // nodes per bucket
#define NBMAX 1024       // supports N <= 65536 (and N <= 2^26 for packing)
#define BCAP 3072        // slab capacity per bucket (E[cnt]=2046, >20 sigma safe)
#define CPAD 16          // bucket_cnt stride (ints): one counter per 64B line
#define PREP_BLOCKS 256  // 1 block/CU; 512 measured WORSE (phase-2 atomic tail, r3)
#define OVF_CAP 65536
#define GB_THREADS 1024  // gatherB block: 16 waves, one bucket per block
#define XW_BLOCKS 256
#define XW_THREADS 512   // 8 waves: waves 0-3 bucket 2bb, waves 4-7 bucket 2bb+1

// r5: one-writer/global-broadcast W staging diverged on graph replay — W stays
//     staged per-block in LDS.
// r7: gatherB invariant at 42.4us under gather ILP restructure -> pattern-BW
//     bound; gather structure frozen (uint2 lane-groups, int LDS list).
// r8: prep||xw block-fusion = no overlap; normalize-late int2 list = +16.5us
//     on gatherB. Both reverted. This round: xw stages W once per block
//     (256x not 782x) via 512-thread blocks striding bucket-pairs.

using half8 = __attribute__((ext_vector_type(8))) _Float16;
using float4v = __attribute__((ext_vector_type(4))) float;
using floatx2 = __attribute__((ext_vector_type(2))) float;

// ---- fused prep: LDS histogram -> padded atomic slab reservation -> place ---
__global__ __launch_bounds__(256) void prep_kernel(const int* __restrict__ src,
                                                   const int* __restrict__ dst,
                                                   int* __restrict__ bucket_cnt,
                                                   int* __restrict__ pairs,
                                                   int* __restrict__ ovfA_cnt,
                                                   int2* __restrict__ ovfA,
                                                   int E, int NB) {
    __shared__ int sbase[NBMAX];  // histogram, then reserved base
    __shared__ int cur[NBMAX];
    const int t = threadIdx.x;
    for (int b = t; b < NB; b += 256) { sbase[b] = 0; cur[b] = 0; }
    __syncthreads();

    int chunk = (((E + (int)gridDim.x - 1) / (int)gridDim.x) + 3) & ~3;  // 4-aligned
    int start = blockIdx.x * chunk;
    int end = min(start + chunk, E);

    // phase 1: histogram dst>>6 for this chunk
    for (int i = start + 4 * t; i < end; i += 4 * 256) {
        if (i + 3 < end) {
            int4 v = *(const int4*)&dst[i];
            atomicAdd(&sbase[v.x >> BSHIFT], 1);
            atomicAdd(&sbase[v.y >> BSHIFT], 1);
            atomicAdd(&sbase[v.z >> BSHIFT], 1);
            atomicAdd(&sbase[v.w >> BSHIFT], 1);
        } else {
            for (int j = i; j < end; ++j) atomicAdd(&sbase[dst[j] >> BSHIFT], 1);
        }
    }
    __syncthreads();

    // phase 2: reserve a contiguous range per bucket (padded -> no line sharing)
    for (int b = t; b < NB; b += 256) {
        int h = sbase[b];
        sbase[b] = h ? atomicAdd(&bucket_cnt[b * CPAD], h) : 0;
    }
    __syncthreads();

    // phase 3: replay chunk (L2-hot) and place packed (src<<6)|dl
    auto place = [&](int dd, int ss) {
        int b = dd >> BSHIFT;
        int p = sbase[b] + atomicAdd(&cur[b], 1);
        if (p < BCAP) {
            pairs[(size_t)b * BCAP + p] = (ss << BSHIFT) | (dd & (BSIZE - 1));
        } else {  // slab overflow (statistically never)
            int q = atomicAdd(ovfA_cnt, 1);
            if (q < OVF_CAP) ovfA[q] = make_int2(dd, ss);
        }
    };

    for (int i = start + 4 * t; i < end; i += 4 * 256) {
        if (i + 3 < end) {
            int4 dv = *(const int4*)&dst[i];
            int4 sv = *(const int4*)&src[i];
            place(dv.x, sv.x);
            place(dv.y, sv.y);
            place(dv.z, sv.z);
            place(dv.w, sv.w);
        } else {
            for (int j = i; j < end; ++j) place(dst[j], src[j]);
        }
    }
}

// ---------------- xw = (x * dinv) @ W^T via MFMA f16 -> fp8 e4m3, sigma cols --
// 256 blocks x 512 threads; each block stages W-fragments ONCE, then strides
// over bucket-PAIRS: waves 0-3 handle bucket 2bb, waves 4-7 bucket 2bb+1.
// Cuts W staging from 782x to 256x (~50MB -> 16MB L2 traffic + fewer barriers)
// while keeping 16 waves/CU (2 blocks x 8 waves). Numerics identical to r7.
// MFMA 16x16x32_f16: A[m=lane&15][k=(lane>>4)*8+j]; B[k][n=lane&15];
// D: col=lane&15, row=(lane>>4)*4+reg.
// xw[row] = 128 fp8 bytes, byte sigma(col) = (col%16)*8 + col/16.
__global__ __launch_bounds__(XW_THREADS) void xw_kernel(
    const float* __restrict__ x, const float* __restrict__ W,
    const int* __restrict__ pairs, const int* __restrict__ bucket_cnt,
    const int* __restrict__ ovfA_cnt, const int2* __restrict__ ovfA,
    unsigned char* __restrict__ xw, int N, int NB) {
    __shared__ _Float16 Bf[128 * 128];  // 32 KB, fragment-ordered
    __shared__ int degX[2 * BSIZE];
    const int t = threadIdx.x;

    // stage B fragments once per block (512 threads: 4 half8 writes each)
    {
        int n = t >> 2;               // 0..127 (output col)
        int jt = n >> 4, nlo = n & 15;
        int kbase = (t & 3) * 32;
#pragma unroll
        for (int o = 0; o < 4; ++o) {
            int k0 = kbase + o * 8;
            float4 f0 = *(const float4*)&W[n * 128 + k0];
            float4 f1 = *(const float4*)&W[n * 128 + k0 + 4];
            int kt = k0 >> 5, quad = (k0 >> 3) & 3;
            half8 h;
            h[0] = (_Float16)f0.x; h[1] = (_Float16)f0.y;
            h[2] = (_Float16)f0.z; h[3] = (_Float16)f0.w;
            h[4] = (_Float16)f1.x; h[5] = (_Float16)f1.y;
            h[6] = (_Float16)f1.z; h[7] = (_Float16)f1.w;
            *(half8*)&Bf[(size_t)(((kt * 8 + jt) * 4 + quad) * 16 + nlo) * 8] = h;
        }
    }
    // (first in-loop barrier covers the staging)

    const int sub = t >> 8;     // 0/1: which bucket of the pair
    const int ht = t & 255;     // thread index within the sub-group
    const int lane = t & 63;
    const int quad = lane >> 4, nlo = lane & 15;
    const int wv = ht >> 6;     // wave within sub (0..3)

    int na = *ovfA_cnt;
    if (na > OVF_CAP) na = OVF_CAP;

    const int npairs = (NB + 1) >> 1;
    for (int bb = blockIdx.x; bb < npairs; bb += XW_BLOCKS) {
        const int b = 2 * bb + sub;
        const bool valid = (b < NB);
        if (ht < BSIZE) degX[sub * BSIZE + ht] = 0;
        __syncthreads();

        if (valid) {  // degree histogram for this bucket (for dinv)
            int cnt = min(bucket_cnt[b * CPAD], BCAP);
            const int* pp = pairs + (size_t)b * BCAP;
            int* dg = degX + sub * BSIZE;
            for (int i = ht; i < cnt; i += 256) atomicAdd(&dg[pp[i] & (BSIZE - 1)], 1);
            if (na > 0) {
                for (int k = ht; k < na; k += 256) {
                    int dd = ovfA[k].x;
                    if ((dd >> BSHIFT) == b) atomicAdd(&dg[dd & (BSIZE - 1)], 1);
                }
            }
        }
        __syncthreads();

        if (valid) {
            const int r0 = b * 64 + wv * 16;
            const int rA = r0 + nlo;
            const int rAc = (rA < N) ? rA : (N - 1);
            const float dv = rsqrtf((float)degX[sub * BSIZE + (rAc - b * 64)] + 1.0f);

            float4v acc[8];
#pragma unroll
            for (int j = 0; j < 8; ++j) acc[j] = (float4v){0.f, 0.f, 0.f, 0.f};

#pragma unroll
            for (int kt = 0; kt < 4; ++kt) {
                const float* xp = x + (size_t)rAc * D + kt * 32 + quad * 8;
                float4 a0 = *(const float4*)xp;
                float4 a1 = *(const float4*)(xp + 4);
                half8 va;
                va[0] = (_Float16)(a0.x * dv); va[1] = (_Float16)(a0.y * dv);
                va[2] = (_Float16)(a0.z * dv); va[3] = (_Float16)(a0.w * dv);
                va[4] = (_Float16)(a1.x * dv); va[5] = (_Float16)(a1.y * dv);
                va[6] = (_Float16)(a1.z * dv); va[7] = (_Float16)(a1.w * dv);
#pragma unroll
                for (int jt = 0; jt < 8; ++jt) {
                    half8 vb = *(half8*)&Bf[(size_t)((kt * 8 + jt) * 64 + lane) * 8];
                    acc[jt] = __builtin_amdgcn_mfma_f32_16x16x32_f16(va, vb, acc[jt], 0, 0, 0);
                }
            }

#pragma unroll
            for (int reg = 0; reg < 4; ++reg) {
                int row = r0 + quad * 4 + reg;
                if (row < N) {
                    int u0 = __builtin_amdgcn_cvt_pk_fp8_f32(acc[0][reg], acc[1][reg], 0, false);
                    u0 = __builtin_amdgcn_cvt_pk_fp8_f32(acc[2][reg], acc[3][reg], u0, true);
                    int u1 = __builtin_amdgcn_cvt_pk_fp8_f32(acc[4][reg], acc[5][reg], 0, false);
                    u1 = __builtin_amdgcn_cvt_pk_fp8_f32(acc[6][reg], acc[7][reg], u1, true);
                    *(uint2*)(xw + (size_t)row * 128 + nlo * 8) = make_uint2((unsigned)u0, (unsigned)u1);
                }
            }
        }
        __syncthreads();  // protect degX re-zero on next iteration
    }
}

// ---------------- gatherB: in-block counting sort + uint2 gather + epilogue --
// r7-exact (42.4us measured; frozen). 4 lane-groups of 16; group g loads edge
// e+g's row as uint2 (8B/lane, 16 lanes = 128B row). Group sums combine via
// shfl_xor(16,32); self/spills post-reduction; group g writes cols 2g,2g+1.
// out[d][c] = x[d][c] + relu(dinv[d]*(xw[d] + sum_e xw[src_e]) + b[c])
// byte s of a row = col ((s%8)*16 + s/8).
__global__ __launch_bounds__(GB_THREADS) void gatherB_kernel(
    const float* __restrict__ x, const unsigned char* __restrict__ xw,
    const int* __restrict__ pairs, const int* __restrict__ bucket_cnt,
    const float* __restrict__ bias, const int* __restrict__ ovfA_cnt,
    const int2* __restrict__ ovfA, float* __restrict__ out, int N) {
    __shared__ int lds_src[BCAP];          // 12 KB
    __shared__ int degL[BSIZE], offs[BSIZE], cur[BSIZE], spillc[BSIZE];
    const int b = blockIdx.x;
    const int t = threadIdx.x;
    if (t < BSIZE) { degL[t] = 0; cur[t] = 0; spillc[t] = 0; }
    __syncthreads();
    const int cnt = min(bucket_cnt[b * CPAD], BCAP);
    int na = *ovfA_cnt;
    if (na > OVF_CAP) na = OVF_CAP;

    // stage 1a: load packed pairs (3 static peels) + LDS histogram (slab only)
    const int* slab = pairs + (size_t)b * BCAP;
    int w0 = 0, w1 = 0, w2 = 0;
    const bool p0 = t < cnt, p1 = t + 1024 < cnt, p2 = t + 2048 < cnt;
    if (p0) { w0 = slab[t];        atomicAdd(&degL[w0 & (BSIZE - 1)], 1); }
    if (p1) { w1 = slab[t + 1024]; atomicAdd(&degL[w1 & (BSIZE - 1)], 1); }
    if (p2) { w2 = slab[t + 2048]; atomicAdd(&degL[w2 & (BSIZE - 1)], 1); }
    // spill counts go to a separate array (dinv only; NOT the LDS list offsets)
    if (na > 0) {
        for (int k = t; k < na; k += GB_THREADS) {
            int dd = ovfA[k].x;
            if ((dd >> BSHIFT) == b) atomicAdd(&spillc[dd & (BSIZE - 1)], 1);
        }
    }
    __syncthreads();

    // stage 1b: exclusive scan of degL (wave 0, shuffle scan over 64 lanes)
    if (t < BSIZE) {
        int v = degL[t];
        int s = v;
#pragma unroll
        for (int o = 1; o < 64; o <<= 1) {
            int u = __shfl_up(s, o, 64);
            if (t >= o) s += u;
        }
        offs[t] = s - v;
    }
    __syncthreads();

    // stage 1c: scatter register-held pairs into node-sorted LDS list
    if (p0) { int dl = w0 & (BSIZE - 1); lds_src[offs[dl] + atomicAdd(&cur[dl], 1)] = w0 >> BSHIFT; }
    if (p1) { int dl = w1 & (BSIZE - 1); lds_src[offs[dl] + atomicAdd(&cur[dl], 1)] = w1 >> BSHIFT; }
    if (p2) { int dl = w2 & (BSIZE - 1); lds_src[offs[dl] + atomicAdd(&cur[dl], 1)] = w2 >> BSHIFT; }
    __syncthreads();

    // stage 2: wave w handles nodes dl = 4w..4w+3
    const int wave = t >> 6, lane = t & 63;
    const int g = lane >> 4, c15 = lane & 15;
    const uint2* xw64 = (const uint2*)xw;  // row r at r*16 + c15 (8B each)

    // this lane's two output cols: byte s = c15*8 + 2g + j, col = (s%8)*16 + s/8
    const int sb0 = c15 * 8 + 2 * g, sb1 = sb0 + 1;
    const int colA = ((sb0 & 7) << 4) + (sb0 >> 3);
    const int colB = ((sb1 & 7) << 4) + (sb1 >> 3);
    const float bA = bias[colA], bB = bias[colB];

    for (int q = 0; q < 4; ++q) {
        int dl = wave * 4 + q;
        int node = b * BSIZE + dl;
        if (node >= N) break;  // wave-uniform
        int start = offs[dl];
        int end = start + degL[dl];
        float dvd = rsqrtf((float)(degL[dl] + spillc[dl]) + 1.0f);
        size_t noff = (size_t)node * D;

        float a0 = 0.f, a1 = 0.f, a2 = 0.f, a3 = 0.f;
        float a4 = 0.f, a5 = 0.f, a6 = 0.f, a7 = 0.f;

#define ACC8(v)                                                              \
    {                                                                        \
        floatx2 q0 = __builtin_amdgcn_cvt_pk_f32_fp8((int)(v).x, false);     \
        floatx2 q1 = __builtin_amdgcn_cvt_pk_f32_fp8((int)(v).x, true);      \
        floatx2 q2 = __builtin_amdgcn_cvt_pk_f32_fp8((int)(v).y, false);     \
        floatx2 q3 = __builtin_amdgcn_cvt_pk_f32_fp8((int)(v).y, true);      \
        a0 += q0.x; a1 += q0.y; a2 += q1.x; a3 += q1.y;                      \
        a4 += q2.x; a5 += q2.y; a6 += q3.x; a7 += q3.y;                      \
    }

        int e = start;
        for (; e + 15 < end; e += 16) {  // 4 independent 8B loads in flight
            int r0 = lds_src[e + 0 + g], r1 = lds_src[e + 4 + g];
            int r2 = lds_src[e + 8 + g], r3 = lds_src[e + 12 + g];
            uint2 v0 = xw64[(size_t)r0 * 16 + c15];
            uint2 v1 = xw64[(size_t)r1 * 16 + c15];
            uint2 v2 = xw64[(size_t)r2 * 16 + c15];
            uint2 v3 = xw64[(size_t)r3 * 16 + c15];
            ACC8(v0) ACC8(v1) ACC8(v2) ACC8(v3)
        }
        for (; e < end; e += 4) {  // masked tail, zero-fill inactive groups
            int idx = e + g;
            uint2 v = make_uint2(0u, 0u);
            if (idx < end) {
                int r = lds_src[idx];
                v = xw64[(size_t)r * 16 + c15];
            }
            ACC8(v)
        }

        // combine the 4 lane-groups: all lanes then hold full per-c15 sums
        a0 += __shfl_xor(a0, 16); a0 += __shfl_xor(a0, 32);
        a1 += __shfl_xor(a1, 16); a1 += __shfl_xor(a1, 32);
        a2 += __shfl_xor(a2, 16); a2 += __shfl_xor(a2, 32);
        a3 += __shfl_xor(a3, 16); a3 += __shfl_xor(a3, 32);
        a4 += __shfl_xor(a4, 16); a4 += __shfl_xor(a4, 32);
        a5 += __shfl_xor(a5, 16); a5 += __shfl_xor(a5, 32);
        a6 += __shfl_xor(a6, 16); a6 += __shfl_xor(a6, 32);
        a7 += __shfl_xor(a7, 16); a7 += __shfl_xor(a7, 32);

        // self term + spills (post-reduction: every lane adds its own c15 words)
        {
            uint2 vs = xw64[(size_t)node * 16 + c15];
            ACC8(vs)
            if (na > 0) {
                for (int k = 0; k < na; ++k) {
                    int2 pr = ovfA[k];
                    if (pr.x == node) {
                        uint2 v = xw64[(size_t)pr.y * 16 + c15];
                        ACC8(v)
                    }
                }
            }
        }
#undef ACC8

        // epilogue: group g writes cols k=2g, 2g+1 (uniform cndmask selects)
        float sA = (g == 0) ? a0 : (g == 1) ? a2 : (g == 2) ? a4 : a6;
        float sB = (g == 0) ? a1 : (g == 1) ? a3 : (g == 2) ? a5 : a7;
        float hA = sA * dvd + bA;
        float hB = sB * dvd + bB;
        out[noff + colA] = x[noff + colA] + (hA > 0.f ? hA : 0.f);
        out[noff + colB] = x[noff + colB] + (hB > 0.f ? hB : 0.f);
    }
}

extern "C" void kernel_launch(void* const* d_in, const int* in_sizes, int n_in,
                              void* d_out, int out_size, void* d_ws, size_t ws_size,
                              hipStream_t stream) {
    const float* x = (const float*)d_in[0];
    const int* ei = (const int*)d_in[1];
    const float* W = (const float*)d_in[2];
    const float* bias = (const float*)d_in[3];
    float* out = (float*)d_out;

    const int N = in_sizes[0] / D;   // 50000
    const int E = in_sizes[1] / 2;   // 1,600,000
    const int* src = ei;
    const int* dst = ei + E;
    const int NB = (N + BSIZE - 1) / BSIZE;  // 782 (<= NBMAX)

    // workspace (~17 MB); bucket_cnt (padded) + ovfA_cnt adjacent -> one memset
    char* p = (char*)d_ws;
    int* pairs = (int*)p;            p += (size_t)NB * BCAP * sizeof(int);      // 9.6 MB
    unsigned char* xw = (unsigned char*)p; p += (size_t)N * 128;                // 6.4 MB
    int* bucket_cnt = (int*)p;       p += (size_t)NBMAX * CPAD * sizeof(int);   // 64 KB
    int* ovfA_cnt = (int*)p;         p += 16;
    int2* ovfA = (int2*)p;           p += (size_t)OVF_CAP * sizeof(int2);       // 0.5 MB

    hipMemsetAsync(bucket_cnt, 0, (size_t)NBMAX * CPAD * sizeof(int) + 16, stream);

    prep_kernel<<<PREP_BLOCKS, 256, 0, stream>>>(src, dst, bucket_cnt, pairs,
                                                 ovfA_cnt, ovfA, E, NB);
    xw_kernel<<<XW_BLOCKS, XW_THREADS, 0, stream>>>(x, W, pairs, bucket_cnt,
                                                    ovfA_cnt, ovfA, xw, N, NB);
    gatherB_kernel<<<NB, GB_THREADS, 0, stream>>>(x, xw, pairs, bucket_cnt,
                                                  bias, ovfA_cnt, ovfA, out, N);
}